// Round 16
// baseline (135.007 us; speedup 1.0000x reference)
//
#include <hip/hip_runtime.h>
#include <hip/hip_bf16.h>
#include <hip/hip_fp16.h>

#define BATCHN 512
#define NV 50
#define NE 2450
#define INSZ 16
#define MH 32
#define NH 256

typedef short s16x8 __attribute__((ext_vector_type(8)));
typedef _Float16 f16x8 __attribute__((ext_vector_type(8)));
typedef float f32x4 __attribute__((ext_vector_type(4)));
typedef float f32x2 __attribute__((ext_vector_type(2)));

#define PRED_OFF (BATCHN * NV * INSZ)   // 409600

// ---- ws layout (bytes) ----
// W2t    f16  [3][32][32]         : 3276800  .. 3282944
// W1t    bf16 [2][3][32][32]      : 3282944  .. 3295232
// Wt1sw  bf16 16384               : 3295232  .. 3328000   ([256][64] XOR-swizzled)
// Wt2sw  bf16 65536               : 3328000  .. 3459072   (4 x [256][64] swizzled)
// Wtmusw bf16 4096                : 3459072  .. 3467264   ([16][256] swizzled)

__device__ __forceinline__ unsigned short f2bf(float x) {
  unsigned int u = __float_as_uint(x);
  unsigned int r = (u + 0x7fffu + ((u >> 16) & 1u)) >> 16;  // RTNE
  return (unsigned short)r;
}
__device__ __forceinline__ unsigned short f2h(float x) {
  return __half_as_ushort(__float2half(x));  // RTNE f32->f16
}
__device__ __forceinline__ unsigned int pk2(float a, float b) {
  return (unsigned int)f2bf(a) | ((unsigned int)f2bf(b) << 16);
}
__device__ __forceinline__ unsigned int cvtpk(float lo, float hi) {
  unsigned int r;
  asm("v_cvt_pk_bf16_f32 %0, %1, %2" : "=v"(r) : "v"(lo), "v"(hi));
  return r;
}
__device__ __forceinline__ unsigned int pkmax0(unsigned int x, unsigned int z) {
  unsigned int r;
  asm("v_pk_max_i16 %0, %1, %2" : "=v"(r) : "v"(x), "v"(z));
  return r;
}
__device__ __forceinline__ unsigned int pkaddh(unsigned int a, unsigned int b) {
  unsigned int r;
  asm("v_pk_add_f16 %0, %1, %2" : "=v"(r) : "v"(a), "v"(b));
  return r;
}
__device__ __forceinline__ void pkfma(f32x2& acc, f32x2 a, f32x2 b) {
  asm("v_pk_fma_f32 %0, %1, %2, %0" : "+v"(acc) : "v"(a), "v"(b));
}

// ---------------- Kernel 1: weight transforms (unchanged) -------------------
__global__ void k_tr(const float* __restrict__ w1, const float* __restrict__ w2,
                     const float* __restrict__ wo1, const float* __restrict__ wo2,
                     const float* __restrict__ wmu,
                     unsigned short* __restrict__ W2t, unsigned short* __restrict__ W1t,
                     unsigned short* __restrict__ Wt1sw, unsigned short* __restrict__ Wt2sw,
                     unsigned short* __restrict__ Wtmusw) {
  int idx = blockIdx.x * 256 + threadIdx.x;
  if (idx < 3072) {                      // W2t[kk][h][c] = w2[(kk+1)*32 + c][h] (f16)
    int c = idx & 31, h = (idx >> 5) & 31, kk = idx >> 10;
    W2t[idx] = f2h(w2[((kk + 1) * 32 + c) * 32 + h]);
  } else if (idx < 9216) {               // W1t[half][kk][n][k] (bf16)
    int j = idx - 3072;
    int k = j & 31, n = (j >> 5) & 31, kk = (j >> 10) % 3, half = j / 3072;
    W1t[j] = f2bf(k < 16 ? w1[((kk + 1) * 32 + half * 16 + k) * 32 + n] : 0.f);
  } else if (idx < 9216 + 16384) {       // Wt1sw
    int j = idx - 9216; int n = j & 255, kl = j >> 8;
    float v = kl < 48 ? wo1[kl * 256 + n] : 0.f;
    Wt1sw[n * 64 + (kl ^ ((n & 7) << 3))] = f2bf(v);
  } else if (idx < 9216 + 16384 + 65536) { // Wt2sw
    int j = idx - (9216 + 16384);
    int c = j >> 14, r = j & 16383;
    int n = r & 255, kl = r >> 8;
    float v = wo2[(c * 64 + kl) * 256 + n];
    Wt2sw[(c * 256 + n) * 64 + (kl ^ ((n & 7) << 3))] = f2bf(v);
  } else if (idx < 9216 + 16384 + 65536 + 4096) { // Wtmusw
    int j = idx - (9216 + 16384 + 65536);
    int n = j & 15, kl = j >> 4;
    Wtmusw[n * 256 + (kl ^ ((n & 7) << 3))] = f2bf(wmu[kl * 16 + n]);
  }
}

// ---------------- Kernel 2: FUSED msg + out-MLP, j-split blocks --------------
// grid (512 batches, 2 j-halves) x 512 thr (8 waves); 40.3 KB LDS -> 4 blk/CU
// = 32 waves/CU. Block (b, jh): receivers jbase..jbase+24 (2 jt tiles of 16),
// ALL 50 senders (4-way parity ih). Phase 1 = scheme-F f16 messages -> agg_l.
// Phase 2 = out-MLP on this block's 25 rows; Wt1/Wt2 staged in 16 KB chunks
// with stride-18-word pad (bank-safe, no XOR on read).
__global__ void __launch_bounds__(512, 8)
k_all(const float* __restrict__ inputs, const float* __restrict__ edges,
      const float* __restrict__ b1, const float* __restrict__ b2,
      const unsigned short* __restrict__ W1t, const unsigned short* __restrict__ W2t,
      const unsigned short* __restrict__ Wt1sw, const float* __restrict__ bo1,
      const unsigned short* __restrict__ Wt2sw, const float* __restrict__ bo2,
      const unsigned short* __restrict__ Wtmusw, const float* __restrict__ bmu,
      float* __restrict__ out) {
  __shared__ __align__(16) char smem[40352];
  unsigned short* S16 = (unsigned short*)(smem);           // [0,10400)      50x104 f16
  unsigned short* R16 = (unsigned short*)(smem + 10400);   // [10400,17056)  32x104 f16
  float* E_lds = (float*)(smem + 17056);                   // [17056,36256)  [50][3][32] f32
  float* comb  = (float*)(smem);                           // [0,12288)   overlays S/R post-loop
  float* agg_l = (float*)(smem + 36256);                   // [36256,40352)  32x32 f32
  unsigned short* WB  = (unsigned short*)(smem);           // [0,18432)   256x36 (stride 18w)
  unsigned short* aug = (unsigned short*)(smem + 18432);   // [18432,23040)  32x72
  unsigned short* P1  = (unsigned short*)(smem + 23040);   // [23040,39936)  32x264

  const int b     = blockIdx.x;
  const int jh    = blockIdx.y;
  const int jbase = jh * 25;
  const int tid   = threadIdx.x;
  const int w     = tid >> 6;     // 0..7
  const int l     = tid & 63;
  const int grp   = l >> 4;       // 0..3
  const int lm    = l & 15;
  const int jt    = w & 1;        // receiver tile (phase 1) -- see below
  const int ih    = w >> 1;       // sender parity 0..3 (phase 1)

  // ======================= PHASE 1: messages =======================
  // stage E: E_lds[i][kk][js] for this block's 25 receivers; dead slots = 0
  for (int x = tid; x < NV * 32; x += 512) {
    int i  = x >> 5;
    int js = x & 31;
    int gj = jbase + js;
    float4 ev = make_float4(0.f, 0.f, 0.f, 0.f);
    if (js < 25 && gj != i) {
      int e = i * 49 + gj - (gj > i ? 1 : 0);
      ev = reinterpret_cast<const float4*>(edges)[b * NE + e];
    }
    int base = i * 96 + js;
    E_lds[base]      = ev.y;      // edge types 1..3 only (SKIP_FIRST)
    E_lds[base + 32] = ev.z;
    E_lds[base + 64] = ev.w;
  }

  // in-block fc1: waves 0-3 -> S tiles 0-3 (all 50 senders); waves 4-5 -> R
  if (w < 6) {
    const int half = (w < 4) ? 1 : 0;   // 1 = send weights (S), 0 = recv (R,+b1)
    const int mt4  = (w < 4) ? w : (w - 4);
    int node  = (w < 4) ? (mt4 * 16 + lm) : (jbase + mt4 * 16 + lm);
    int nodec = node < NV ? node : NV - 1;
    s16x8 af = {0, 0, 0, 0, 0, 0, 0, 0};
    if (grp < 2) {
      const float4* ip = reinterpret_cast<const float4*>(inputs) + (b * NV + nodec) * 4 + grp * 2;
      float4 x0 = ip[0], x1 = ip[1];
      union { unsigned int u[4]; s16x8 v; } U;
      U.u[0] = cvtpk(x0.x, x0.y); U.u[1] = cvtpk(x0.z, x0.w);
      U.u[2] = cvtpk(x1.x, x1.y); U.u[3] = cvtpk(x1.z, x1.w);
      af = U.v;
    }
    unsigned short* dst = half ? S16 : R16;
#pragma unroll
    for (int kk = 0; kk < 3; ++kk) {
#pragma unroll
      for (int nt = 0; nt < 2; ++nt) {
        int h = lm + 16 * nt;
        s16x8 bf = *reinterpret_cast<const s16x8*>(W1t + ((half * 3 + kk) * 32 + h) * 32 + grp * 8);
        f32x4 C;
        if (half == 0) { float bv = b1[(kk + 1) * 32 + h]; C = f32x4{bv, bv, bv, bv}; }
        else C = f32x4{0.f, 0.f, 0.f, 0.f};
        f32x4 o = __builtin_amdgcn_mfma_f32_16x16x32_bf16(af, bf, C, 0, 0, 0);
#pragma unroll
        for (int rr = 0; rr < 4; ++rr) {
          int n2 = mt4 * 16 + grp * 4 + rr;
          if (half == 0) {
            dst[n2 * 104 + kk * 32 + h] = f2h(o[rr]);     // R: 32 local rows
          } else if (n2 < NV) {
            dst[n2 * 104 + kk * 32 + h] = f2h(o[rr]);     // S: 50 rows
          }
        }
      }
    }
  }

  // per-wave persistent fragments (f16 W2 B-frags + bias scalars)
  f16x8 Bf[3][2];
  float cb[3][2];
#pragma unroll
  for (int kk = 0; kk < 3; ++kk)
#pragma unroll
    for (int nt = 0; nt < 2; ++nt) {
      int h = lm + 16 * nt;
      Bf[kk][nt] = *reinterpret_cast<const f16x8*>(W2t + (kk * 32 + h) * 32 + grp * 8);
      cb[kk][nt] = b2[(kk + 1) * 32 + h];
    }
  __syncthreads();

  // Rh: this wave's 16 receiver rows in f16 (12 u32)
  unsigned int Rh[3][4];
  {
    int jr = jt * 16 + lm;        // local row 0..31
#pragma unroll
    for (int kk = 0; kk < 3; ++kk) {
      uint4 rv = *reinterpret_cast<const uint4*>(&R16[jr * 104 + kk * 32 + grp * 8]);
      Rh[kk][0] = rv.x; Rh[kk][1] = rv.y; Rh[kk][2] = rv.z; Rh[kk][3] = rv.w;
    }
  }

  const int slot0 = jt * 16 + grp * 4;    // 0..28, within 32

  f32x2 acc0a = {0.f, 0.f}, acc0b = {0.f, 0.f};
  f32x2 acc1a = {0.f, 0.f}, acc1b = {0.f, 0.f};

#pragma unroll 4
  for (int i = ih; i < NV; i += 4) {
    const float* Eb = &E_lds[i * 96 + slot0];
#pragma unroll
    for (int kk = 0; kk < 3; ++kk) {
      uint4 sv = *reinterpret_cast<const uint4*>(&S16[i * 104 + kk * 32 + grp * 8]);
      f32x4 ev = *reinterpret_cast<const f32x4*>(Eb + kk * 32);
      union { unsigned int u[4]; f16x8 v; } U;
      U.u[0] = pkmax0(pkaddh(Rh[kk][0], sv.x), 0u);
      U.u[1] = pkmax0(pkaddh(Rh[kk][1], sv.y), 0u);
      U.u[2] = pkmax0(pkaddh(Rh[kk][2], sv.z), 0u);
      U.u[3] = pkmax0(pkaddh(Rh[kk][3], sv.w), 0u);
      f32x4 C0 = f32x4{cb[kk][0], cb[kk][0], cb[kk][0], cb[kk][0]};
      f32x4 C1 = f32x4{cb[kk][1], cb[kk][1], cb[kk][1], cb[kk][1]};
      f32x4 d0 = __builtin_amdgcn_mfma_f32_16x16x32_f16(U.v, Bf[kk][0], C0, 0, 0, 0);
      f32x4 d1 = __builtin_amdgcn_mfma_f32_16x16x32_f16(U.v, Bf[kk][1], C1, 0, 0, 0);
      f32x2 ea = {ev[0], ev[1]}, eb = {ev[2], ev[3]};
      f32x2 r0a = {fmaxf(d0[0], 0.f), fmaxf(d0[1], 0.f)};
      f32x2 r0b = {fmaxf(d0[2], 0.f), fmaxf(d0[3], 0.f)};
      f32x2 r1a = {fmaxf(d1[0], 0.f), fmaxf(d1[1], 0.f)};
      f32x2 r1b = {fmaxf(d1[2], 0.f), fmaxf(d1[3], 0.f)};
      pkfma(acc0a, r0a, ea); pkfma(acc0b, r0b, eb);
      pkfma(acc1a, r1a, ea); pkfma(acc1b, r1b, eb);
    }
  }
  __syncthreads();   // S16/R16 dead everywhere -> comb may overlay

  // combine 4 parity waves via comb (ih 1..3 write, ih 0 sums); write agg_l
  if (ih != 0) {
    int cbase = (((ih - 1) * 2 + jt) * 64 + l) * 8;
    *reinterpret_cast<f32x2*>(&comb[cbase])     = acc0a;
    *reinterpret_cast<f32x2*>(&comb[cbase + 2]) = acc0b;
    *reinterpret_cast<f32x2*>(&comb[cbase + 4]) = acc1a;
    *reinterpret_cast<f32x2*>(&comb[cbase + 6]) = acc1b;
  }
  __syncthreads();
  if (ih == 0) {
#pragma unroll
    for (int p = 0; p < 3; ++p) {
      int cbase = ((p * 2 + jt) * 64 + l) * 8;
      acc0a += *reinterpret_cast<const f32x2*>(&comb[cbase]);
      acc0b += *reinterpret_cast<const f32x2*>(&comb[cbase + 2]);
      acc1a += *reinterpret_cast<const f32x2*>(&comb[cbase + 4]);
      acc1b += *reinterpret_cast<const f32x2*>(&comb[cbase + 6]);
    }
    float a0v[4] = {acc0a[0], acc0a[1], acc0b[0], acc0b[1]};
    float a1v[4] = {acc1a[0], acc1a[1], acc1b[0], acc1b[1]};
#pragma unroll
    for (int rr = 0; rr < 4; ++rr) {
      int j = jt * 16 + grp * 4 + rr;     // local row
      if (j < 25) {
        agg_l[j * 32 + lm]      = a0v[rr];
        agg_l[j * 32 + 16 + lm] = a1v[rr];
      }
    }
  }
  __syncthreads();

  // ======================= PHASE 2: out-MLP (32-row tile) =======================
  const int rowt = w & 1;
  const int nq   = w >> 1;        // 0..3 -> n columns nq*64..+63
  const int rowA = rowt * 16 + lm;
  const int kgrp = grp * 8;
  const int rbase = rowt * 16 + grp * 4;

  // aug build (rows 0..31; rows >= 25 zero)
  if (tid < 128) {
    int row = tid >> 2, q = tid & 3;
    uint2 u0; uint4 u1;
    if (row < 25) {
      float4 iv = reinterpret_cast<const float4*>(inputs)[(b * NV + jbase + row) * 4 + q];
      u0.x = pk2(iv.x, iv.y); u0.y = pk2(iv.z, iv.w);
      f32x4 a0 = *reinterpret_cast<const f32x4*>(&agg_l[row * 32 + q * 8]);
      f32x4 a1 = *reinterpret_cast<const f32x4*>(&agg_l[row * 32 + q * 8 + 4]);
      u1.x = pk2(a0[0], a0[1]); u1.y = pk2(a0[2], a0[3]);
      u1.z = pk2(a1[0], a1[1]); u1.w = pk2(a1[2], a1[3]);
    } else { u0.x = u0.y = 0u; u1.x = u1.y = u1.z = u1.w = 0u; }
    *reinterpret_cast<uint2*>(&aug[row * 72 + q * 4]) = u0;
    *reinterpret_cast<uint4*>(&aug[row * 72 + 16 + q * 8]) = u1;
    uint2 uz; uz.x = 0u; uz.y = 0u;
    *reinterpret_cast<uint2*>(&aug[row * 72 + 48 + q * 4]) = uz;
  }

  // fc1: 2 staged chunks of Wt1 (kc = chunk), stride-18-word WB
  f32x4 acc1[4];
#pragma unroll
  for (int nt = 0; nt < 4; ++nt) acc1[nt] = f32x4{0.f, 0.f, 0.f, 0.f};
  for (int c = 0; c < 2; ++c) {
    for (int x = tid; x < 2048; x += 512) {      // 256 rows x 8 q-groups
      int n = x >> 3, q = x & 7;
      int soff = (c * 32 + q * 4) ^ ((n & 7) << 3);
      uint2 v = *reinterpret_cast<const uint2*>(Wt1sw + n * 64 + soff);
      *reinterpret_cast<uint2*>(reinterpret_cast<unsigned int*>(WB) + n * 18 + q * 2) = v;
    }
    __syncthreads();
    s16x8 af = *reinterpret_cast<const s16x8*>(&aug[rowA * 72 + c * 32 + kgrp]);
#pragma unroll
    for (int nt = 0; nt < 4; ++nt) {
      int n = lm + 16 * (nq * 4 + nt);
      s16x8 bf = *reinterpret_cast<const s16x8*>(&WB[n * 36 + grp * 8]);
      acc1[nt] = __builtin_amdgcn_mfma_f32_16x16x32_bf16(af, bf, acc1[nt], 0, 0, 0);
    }
    __syncthreads();
  }
#pragma unroll
  for (int nt = 0; nt < 4; ++nt) {
    int n = lm + 16 * (nq * 4 + nt);
    float bias = bo1[n];
#pragma unroll
    for (int rr = 0; rr < 4; ++rr) {
      float v = acc1[nt][rr] + bias; v = v > 0.f ? v : 0.f;
      P1[(rbase + rr) * 264 + n] = f2bf(v);
    }
  }

  // fc2: 8 staged chunks of Wt2 (kc = chunk)
  f32x4 acc2[4];
#pragma unroll
  for (int nt = 0; nt < 4; ++nt) acc2[nt] = f32x4{0.f, 0.f, 0.f, 0.f};
  for (int c = 0; c < 8; ++c) {
    const unsigned short* src = Wt2sw + (c >> 1) * 16384;
    int khalf = c & 1;
    for (int x = tid; x < 2048; x += 512) {
      int n = x >> 3, q = x & 7;
      int soff = (khalf * 32 + q * 4) ^ ((n & 7) << 3);
      uint2 v = *reinterpret_cast<const uint2*>(src + n * 64 + soff);
      *reinterpret_cast<uint2*>(reinterpret_cast<unsigned int*>(WB) + n * 18 + q * 2) = v;
    }
    __syncthreads();   // also covers P1 fc1-writes before first read
    s16x8 af = *reinterpret_cast<const s16x8*>(&P1[rowA * 264 + c * 32 + kgrp]);
#pragma unroll
    for (int nt = 0; nt < 4; ++nt) {
      int n = lm + 16 * (nq * 4 + nt);
      s16x8 bf = *reinterpret_cast<const s16x8*>(&WB[n * 36 + grp * 8]);
      acc2[nt] = __builtin_amdgcn_mfma_f32_16x16x32_bf16(af, bf, acc2[nt], 0, 0, 0);
    }
    __syncthreads();
  }
  // epilogue: write pred (f32 out, masked) + P1 bf16 (for mu)
#pragma unroll
  for (int nt = 0; nt < 4; ++nt) {
    int n = lm + 16 * (nq * 4 + nt);
    float bias = bo2[n];
#pragma unroll
    for (int rr = 0; rr < 4; ++rr) {
      int row = rbase + rr;
      float v = acc2[nt][rr] + bias; v = v > 0.f ? v : 0.f;
      if (row < 25) out[PRED_OFF + (b * NV + jbase + row) * 256 + n] = v;
      P1[row * 264 + n] = f2bf(v);
    }
  }
  // stage Wtmusw (8 KB = 512 uint4, one per thread) into WB
  reinterpret_cast<uint4*>(WB)[tid] = reinterpret_cast<const uint4*>(Wtmusw)[tid];
  __syncthreads();

  // mu: waves with nq == 0 (both row tiles)
  if (nq == 0) {
    const int xo = (lm & 7) << 3;
    f32x4 accm = {0.f, 0.f, 0.f, 0.f};
#pragma unroll
    for (int kc = 0; kc < 8; ++kc) {
      s16x8 af = *reinterpret_cast<const s16x8*>(&P1[rowA * 264 + kc * 32 + kgrp]);
      s16x8 bf = *reinterpret_cast<const s16x8*>(&WB[lm * 256 + ((kc * 32 + kgrp) ^ xo)]);
      accm = __builtin_amdgcn_mfma_f32_16x16x32_bf16(af, bf, accm, 0, 0, 0);
    }
    float bias = bmu[lm];
#pragma unroll
    for (int rr = 0; rr < 4; ++rr) {
      int row = rbase + rr;
      if (row < 25) out[(b * NV + jbase + row) * 16 + lm] = accm[rr] + bias;
    }
  }
}

extern "C" void kernel_launch(void* const* d_in, const int* in_sizes, int n_in,
                              void* d_out, int out_size, void* d_ws, size_t ws_size,
                              hipStream_t stream) {
  const float* inputs = (const float*)d_in[0];
  const float* edges  = (const float*)d_in[1];
  const float* w1     = (const float*)d_in[2];
  const float* b1     = (const float*)d_in[3];
  const float* w2     = (const float*)d_in[4];
  const float* b2     = (const float*)d_in[5];
  const float* wo1    = (const float*)d_in[6];
  const float* bo1    = (const float*)d_in[7];
  const float* wo2    = (const float*)d_in[8];
  const float* bo2    = (const float*)d_in[9];
  const float* wmu    = (const float*)d_in[10];
  const float* bmu    = (const float*)d_in[11];
  float* out = (float*)d_out;

  char* ws = (char*)d_ws;
  unsigned short* W2t    = (unsigned short*)(ws + 3276800);
  unsigned short* W1t    = (unsigned short*)(ws + 3282944);
  unsigned short* Wt1sw  = (unsigned short*)(ws + 3295232);
  unsigned short* Wt2sw  = (unsigned short*)(ws + 3328000);
  unsigned short* Wtmusw = (unsigned short*)(ws + 3459072);

  k_tr<<<372, 256, 0, stream>>>(w1, w2, wo1, wo2, wmu, W2t, W1t, Wt1sw, Wt2sw, Wtmusw);
  k_all<<<dim3(512, 2), 512, 0, stream>>>(inputs, edges, b1, b2, W1t, W2t,
                                          Wt1sw, bo1, Wt2sw, bo2, Wtmusw, bmu, out);
}

// Round 17
// 56.330 us; speedup vs baseline: 2.3967x; 2.3967x over previous
//
#include <hip/hip_runtime.h>
#include <hip/hip_bf16.h>
#include <hip/hip_fp16.h>

#define BATCHN 512
#define NV 50
#define NE 2450
#define INSZ 16
#define MH 32
#define NH 256

typedef short s16x8 __attribute__((ext_vector_type(8)));
typedef _Float16 f16x8 __attribute__((ext_vector_type(8)));
typedef float f32x4 __attribute__((ext_vector_type(4)));
typedef float f32x2 __attribute__((ext_vector_type(2)));

#define PRED_OFF (BATCHN * NV * INSZ)   // 409600

// ---- ws layout (bytes) ----
// W2t    f16  [3][32][32]         : 3276800  .. 3282944
// W1t    bf16 [2][3][32][32]      : 3282944  .. 3295232
// Wt1sw  bf16 16384               : 3295232  .. 3328000   ([256][64] XOR-swizzled)
// Wt2sw  bf16 65536               : 3328000  .. 3459072   (4 x [256][64] swizzled)
// Wtmusw bf16 4096                : 3459072  .. 3467264   ([16][256] swizzled)

__device__ __forceinline__ unsigned short f2bf(float x) {
  unsigned int u = __float_as_uint(x);
  unsigned int r = (u + 0x7fffu + ((u >> 16) & 1u)) >> 16;  // RTNE
  return (unsigned short)r;
}
__device__ __forceinline__ unsigned short f2h(float x) {
  return __half_as_ushort(__float2half(x));  // RTNE f32->f16
}
__device__ __forceinline__ unsigned int pk2(float a, float b) {
  return (unsigned int)f2bf(a) | ((unsigned int)f2bf(b) << 16);
}
__device__ __forceinline__ unsigned int cvtpk(float lo, float hi) {
  unsigned int r;
  asm("v_cvt_pk_bf16_f32 %0, %1, %2" : "=v"(r) : "v"(lo), "v"(hi));
  return r;
}
__device__ __forceinline__ unsigned int pkmax0(unsigned int x, unsigned int z) {
  unsigned int r;
  asm("v_pk_max_i16 %0, %1, %2" : "=v"(r) : "v"(x), "v"(z));
  return r;
}
__device__ __forceinline__ unsigned int pkaddh(unsigned int a, unsigned int b) {
  unsigned int r;
  asm("v_pk_add_f16 %0, %1, %2" : "=v"(r) : "v"(a), "v"(b));
  return r;
}
__device__ __forceinline__ void pkfma(f32x2& acc, f32x2 a, f32x2 b) {
  asm("v_pk_fma_f32 %0, %1, %2, %0" : "+v"(acc) : "v"(a), "v"(b));
}

// ---------------- Kernel 1: weight transforms (unchanged) -------------------
__global__ void k_tr(const float* __restrict__ w1, const float* __restrict__ w2,
                     const float* __restrict__ wo1, const float* __restrict__ wo2,
                     const float* __restrict__ wmu,
                     unsigned short* __restrict__ W2t, unsigned short* __restrict__ W1t,
                     unsigned short* __restrict__ Wt1sw, unsigned short* __restrict__ Wt2sw,
                     unsigned short* __restrict__ Wtmusw) {
  int idx = blockIdx.x * 256 + threadIdx.x;
  if (idx < 3072) {                      // W2t[kk][h][c] = w2[(kk+1)*32 + c][h] (f16)
    int c = idx & 31, h = (idx >> 5) & 31, kk = idx >> 10;
    W2t[idx] = f2h(w2[((kk + 1) * 32 + c) * 32 + h]);
  } else if (idx < 9216) {               // W1t[half][kk][n][k] (bf16)
    int j = idx - 3072;
    int k = j & 31, n = (j >> 5) & 31, kk = (j >> 10) % 3, half = j / 3072;
    W1t[j] = f2bf(k < 16 ? w1[((kk + 1) * 32 + half * 16 + k) * 32 + n] : 0.f);
  } else if (idx < 9216 + 16384) {       // Wt1sw
    int j = idx - 9216; int n = j & 255, kl = j >> 8;
    float v = kl < 48 ? wo1[kl * 256 + n] : 0.f;
    Wt1sw[n * 64 + (kl ^ ((n & 7) << 3))] = f2bf(v);
  } else if (idx < 9216 + 16384 + 65536) { // Wt2sw
    int j = idx - (9216 + 16384);
    int c = j >> 14, r = j & 16383;
    int n = r & 255, kl = r >> 8;
    float v = wo2[(c * 64 + kl) * 256 + n];
    Wt2sw[(c * 256 + n) * 64 + (kl ^ ((n & 7) << 3))] = f2bf(v);
  } else if (idx < 9216 + 16384 + 65536 + 4096) { // Wtmusw
    int j = idx - (9216 + 16384 + 65536);
    int n = j & 15, kl = j >> 4;
    Wtmusw[n * 256 + (kl ^ ((n & 7) << 3))] = f2bf(wmu[kl * 16 + n]);
  }
}

// ---------------- Kernel 2: FUSED msg + out-MLP, j-split blocks --------------
// grid (512 batches, 2 j-halves) x 512 thr (8 waves); ~73 KB LDS -> 2 blk/CU.
// 1024 blocks = 4 sequential executions per CU slot-pair -> block replacement
// de-phases co-resident blocks (phase-1 loop overlaps neighbor's fc2 chunks).
// Phase 1: 25 receivers (jt = w&1 row tiles), ALL 50 senders 4-way parity
// (ih = w>>1, stride 4), f16 hidden state, MFMA 16x16x32_f16.
// Phase 2: 32-row out-MLP, waves = 2 rowt x 4 n-quarters, R15 WB staging.
__global__ void __launch_bounds__(512, 4)
k_all(const float* __restrict__ inputs, const float* __restrict__ edges,
      const float* __restrict__ b1, const float* __restrict__ b2,
      const unsigned short* __restrict__ W1t, const unsigned short* __restrict__ W2t,
      const unsigned short* __restrict__ Wt1sw, const float* __restrict__ bo1,
      const unsigned short* __restrict__ Wt2sw, const float* __restrict__ bo2,
      const unsigned short* __restrict__ Wtmusw, const float* __restrict__ bmu,
      float* __restrict__ out) {
  __shared__ __align__(16) char smem[73120];
  unsigned short* S16 = (unsigned short*)(smem);           // [0,10400)     50x104 f16
  unsigned short* R16 = (unsigned short*)(smem + 10400);   // [10400,17056) 32x104 f16
  float* E_lds = (float*)(smem + 17056);                   // [17056,36256) [50][3][32] f32
  float* agg_l = (float*)(smem + 36256);                   // [36256,40352) 32x32 f32
  float* comb  = (float*)(smem);                           // [0,12288) overlays S/R post-loop
  unsigned short* aug = (unsigned short*)(smem + 17056);   // [17056,21664) 32x72 (E dead)
  unsigned short* P1  = (unsigned short*)(smem);           // [0,16896) 32x264 (comb dead)
  unsigned short* WB  = (unsigned short*)(smem + 40352);   // [40352,73120) 32 KB

  const int b     = blockIdx.x;
  const int jbase = blockIdx.y * 25;
  const int tid   = threadIdx.x;
  const int w     = tid >> 6;     // 0..7
  const int l     = tid & 63;
  const int grp   = l >> 4;       // 0..3
  const int lm    = l & 15;
  const int jt    = w & 1;        // receiver tile (phase 1)
  const int ih    = w >> 1;       // sender parity 0..3 (phase 1)

  // ======================= PHASE 1: messages =======================
  // stage E: E_lds[i][kk][js] for this block's 25 receivers; js >= 25 zero
  for (int x = tid; x < NV * 32; x += 512) {
    int i  = x >> 5;
    int js = x & 31;
    int gj = jbase + js;
    float4 ev = make_float4(0.f, 0.f, 0.f, 0.f);
    if (js < 25 && gj != i) {
      int e = i * 49 + gj - (gj > i ? 1 : 0);
      ev = reinterpret_cast<const float4*>(edges)[b * NE + e];
    }
    int base = i * 96 + js;
    E_lds[base]      = ev.y;      // edge types 1..3 only (SKIP_FIRST)
    E_lds[base + 32] = ev.z;
    E_lds[base + 64] = ev.w;
  }

  // in-block fc1: waves 0-3 -> S (50 rows, 4 tiles); waves 4-5 -> R (32 local rows)
  if (w < 6) {
    const int half = (w < 4) ? 1 : 0;   // 1 = send weights (S), 0 = recv (R, +b1)
    const int mt4  = (w < 4) ? w : (w - 4);
    int node  = (w < 4) ? (mt4 * 16 + lm) : (jbase + mt4 * 16 + lm);
    int nodec = node < NV ? node : NV - 1;
    s16x8 af = {0, 0, 0, 0, 0, 0, 0, 0};
    if (grp < 2) {
      const float4* ip = reinterpret_cast<const float4*>(inputs) + (b * NV + nodec) * 4 + grp * 2;
      float4 x0 = ip[0], x1 = ip[1];
      union { unsigned int u[4]; s16x8 v; } U;
      U.u[0] = cvtpk(x0.x, x0.y); U.u[1] = cvtpk(x0.z, x0.w);
      U.u[2] = cvtpk(x1.x, x1.y); U.u[3] = cvtpk(x1.z, x1.w);
      af = U.v;
    }
    unsigned short* dst = half ? S16 : R16;
#pragma unroll
    for (int kk = 0; kk < 3; ++kk) {
#pragma unroll
      for (int nt = 0; nt < 2; ++nt) {
        int h = lm + 16 * nt;
        s16x8 bf = *reinterpret_cast<const s16x8*>(W1t + ((half * 3 + kk) * 32 + h) * 32 + grp * 8);
        f32x4 C;
        if (half == 0) { float bv = b1[(kk + 1) * 32 + h]; C = f32x4{bv, bv, bv, bv}; }
        else C = f32x4{0.f, 0.f, 0.f, 0.f};
        f32x4 o = __builtin_amdgcn_mfma_f32_16x16x32_bf16(af, bf, C, 0, 0, 0);
#pragma unroll
        for (int rr = 0; rr < 4; ++rr) {
          int n2 = mt4 * 16 + grp * 4 + rr;
          if (half == 0 || n2 < NV) dst[n2 * 104 + kk * 32 + h] = f2h(o[rr]);
        }
      }
    }
  }

  // per-wave persistent fragments (f16 W2 B-frags + bias scalars)
  f16x8 Bf[3][2];
  float cb[3][2];
#pragma unroll
  for (int kk = 0; kk < 3; ++kk)
#pragma unroll
    for (int nt = 0; nt < 2; ++nt) {
      int h = lm + 16 * nt;
      Bf[kk][nt] = *reinterpret_cast<const f16x8*>(W2t + (kk * 32 + h) * 32 + grp * 8);
      cb[kk][nt] = b2[(kk + 1) * 32 + h];
    }
  __syncthreads();

  // Rh: this wave's 16 receiver rows in f16 (12 u32)
  unsigned int Rh[3][4];
  {
    int jr = jt * 16 + lm;        // local row 0..31 (rows >= 25 garbage, E=0)
#pragma unroll
    for (int kk = 0; kk < 3; ++kk) {
      uint4 rv = *reinterpret_cast<const uint4*>(&R16[jr * 104 + kk * 32 + grp * 8]);
      Rh[kk][0] = rv.x; Rh[kk][1] = rv.y; Rh[kk][2] = rv.z; Rh[kk][3] = rv.w;
    }
  }

  const int slot0 = jt * 16 + grp * 4;    // 0..28 (+rr up to 31)

  f32x2 acc0a = {0.f, 0.f}, acc0b = {0.f, 0.f};
  f32x2 acc1a = {0.f, 0.f}, acc1b = {0.f, 0.f};

#pragma unroll 4
  for (int i = ih; i < NV; i += 4) {
    const float* Eb = &E_lds[i * 96 + slot0];
#pragma unroll
    for (int kk = 0; kk < 3; ++kk) {
      uint4 sv = *reinterpret_cast<const uint4*>(&S16[i * 104 + kk * 32 + grp * 8]);
      f32x4 ev = *reinterpret_cast<const f32x4*>(Eb + kk * 32);
      union { unsigned int u[4]; f16x8 v; } U;
      U.u[0] = pkmax0(pkaddh(Rh[kk][0], sv.x), 0u);
      U.u[1] = pkmax0(pkaddh(Rh[kk][1], sv.y), 0u);
      U.u[2] = pkmax0(pkaddh(Rh[kk][2], sv.z), 0u);
      U.u[3] = pkmax0(pkaddh(Rh[kk][3], sv.w), 0u);
      f32x4 C0 = f32x4{cb[kk][0], cb[kk][0], cb[kk][0], cb[kk][0]};
      f32x4 C1 = f32x4{cb[kk][1], cb[kk][1], cb[kk][1], cb[kk][1]};
      f32x4 d0 = __builtin_amdgcn_mfma_f32_16x16x32_f16(U.v, Bf[kk][0], C0, 0, 0, 0);
      f32x4 d1 = __builtin_amdgcn_mfma_f32_16x16x32_f16(U.v, Bf[kk][1], C1, 0, 0, 0);
      f32x2 ea = {ev[0], ev[1]}, eb = {ev[2], ev[3]};
      f32x2 r0a = {fmaxf(d0[0], 0.f), fmaxf(d0[1], 0.f)};
      f32x2 r0b = {fmaxf(d0[2], 0.f), fmaxf(d0[3], 0.f)};
      f32x2 r1a = {fmaxf(d1[0], 0.f), fmaxf(d1[1], 0.f)};
      f32x2 r1b = {fmaxf(d1[2], 0.f), fmaxf(d1[3], 0.f)};
      pkfma(acc0a, r0a, ea); pkfma(acc0b, r0b, eb);
      pkfma(acc1a, r1a, ea); pkfma(acc1b, r1b, eb);
    }
  }
  __syncthreads();   // S16/R16 now dead -> comb may overlay

  // combine 4 parity waves (ih 1..3 write, ih 0 sums); write agg_l
  if (ih != 0) {
    int cbase = (((ih - 1) * 2 + jt) * 64 + l) * 8;
    *reinterpret_cast<f32x2*>(&comb[cbase])     = acc0a;
    *reinterpret_cast<f32x2*>(&comb[cbase + 2]) = acc0b;
    *reinterpret_cast<f32x2*>(&comb[cbase + 4]) = acc1a;
    *reinterpret_cast<f32x2*>(&comb[cbase + 6]) = acc1b;
  }
  __syncthreads();
  if (ih == 0) {
#pragma unroll
    for (int p = 0; p < 3; ++p) {
      int cbase = ((p * 2 + jt) * 64 + l) * 8;
      acc0a += *reinterpret_cast<const f32x2*>(&comb[cbase]);
      acc0b += *reinterpret_cast<const f32x2*>(&comb[cbase + 2]);
      acc1a += *reinterpret_cast<const f32x2*>(&comb[cbase + 4]);
      acc1b += *reinterpret_cast<const f32x2*>(&comb[cbase + 6]);
    }
    float a0v[4] = {acc0a[0], acc0a[1], acc0b[0], acc0b[1]};
    float a1v[4] = {acc1a[0], acc1a[1], acc1b[0], acc1b[1]};
#pragma unroll
    for (int rr = 0; rr < 4; ++rr) {
      int j = jt * 16 + grp * 4 + rr;     // local row
      if (j < 25) {
        agg_l[j * 32 + lm]      = a0v[rr];
        agg_l[j * 32 + 16 + lm] = a1v[rr];
      }
    }
  }
  __syncthreads();

  // ======================= PHASE 2: out-MLP (32-row tile) =======================
  const int xo    = (lm & 7) << 3;
  const int rowt  = w & 1;
  const int nq    = w >> 1;       // 0..3 -> n quarter
  const int rowA  = rowt * 16 + lm;
  const int kgrp  = grp * 8;
  const int rbase = rowt * 16 + grp * 4;

  // aug build (rows 0..31; rows >= 25 zero) + stage full Wt1sw into WB
  if (tid < 128) {
    int row = tid >> 2, q = tid & 3;
    uint2 u0; uint4 u1;
    if (row < 25) {
      float4 iv = reinterpret_cast<const float4*>(inputs)[(b * NV + jbase + row) * 4 + q];
      u0.x = pk2(iv.x, iv.y); u0.y = pk2(iv.z, iv.w);
      f32x4 a0 = *reinterpret_cast<const f32x4*>(&agg_l[row * 32 + q * 8]);
      f32x4 a1 = *reinterpret_cast<const f32x4*>(&agg_l[row * 32 + q * 8 + 4]);
      u1.x = pk2(a0[0], a0[1]); u1.y = pk2(a0[2], a0[3]);
      u1.z = pk2(a1[0], a1[1]); u1.w = pk2(a1[2], a1[3]);
    } else { u0.x = u0.y = 0u; u1.x = u1.y = u1.z = u1.w = 0u; }
    *reinterpret_cast<uint2*>(&aug[row * 72 + q * 4]) = u0;
    *reinterpret_cast<uint4*>(&aug[row * 72 + 16 + q * 8]) = u1;
    uint2 uz; uz.x = 0u; uz.y = 0u;
    *reinterpret_cast<uint2*>(&aug[row * 72 + 48 + q * 4]) = uz;
  }
  {
    const uint4* src = reinterpret_cast<const uint4*>(Wt1sw);
    for (int i2 = tid; i2 < 2048; i2 += 512) reinterpret_cast<uint4*>(WB)[i2] = src[i2];
  }
  __syncthreads();

  // fc1: aug[32x64] @ Wt1 -> P1 [32x256]
  f32x4 acc1[4];
#pragma unroll
  for (int nt = 0; nt < 4; ++nt) acc1[nt] = f32x4{0.f, 0.f, 0.f, 0.f};
#pragma unroll
  for (int kc = 0; kc < 2; ++kc) {
    s16x8 af = *reinterpret_cast<const s16x8*>(&aug[rowA * 72 + kc * 32 + kgrp]);
#pragma unroll
    for (int nt = 0; nt < 4; ++nt) {
      int n = lm + 16 * (nq * 4 + nt);
      s16x8 bf = *reinterpret_cast<const s16x8*>(&WB[n * 64 + ((kc * 32 + kgrp) ^ xo)]);
      acc1[nt] = __builtin_amdgcn_mfma_f32_16x16x32_bf16(af, bf, acc1[nt], 0, 0, 0);
    }
  }
#pragma unroll
  for (int nt = 0; nt < 4; ++nt) {
    int n = lm + 16 * (nq * 4 + nt);
    float bias = bo1[n];
#pragma unroll
    for (int rr = 0; rr < 4; ++rr) {
      float v = acc1[nt][rr] + bias; v = v > 0.f ? v : 0.f;
      P1[(rbase + rr) * 264 + n] = f2bf(v);
    }
  }
  __syncthreads();   // WB (Wt1) readers + P1 writers done

  // fc2: P1 @ Wt2 (4 staged chunks)
  f32x4 acc2[4];
#pragma unroll
  for (int nt = 0; nt < 4; ++nt) acc2[nt] = f32x4{0.f, 0.f, 0.f, 0.f};
  for (int c = 0; c < 4; ++c) {
    const uint4* src = reinterpret_cast<const uint4*>(Wt2sw + c * 16384);
    for (int i2 = tid; i2 < 2048; i2 += 512) reinterpret_cast<uint4*>(WB)[i2] = src[i2];
    __syncthreads();
#pragma unroll
    for (int kcl = 0; kcl < 2; ++kcl) {
      int kc = c * 2 + kcl;
      s16x8 af = *reinterpret_cast<const s16x8*>(&P1[rowA * 264 + kc * 32 + kgrp]);
#pragma unroll
      for (int nt = 0; nt < 4; ++nt) {
        int n = lm + 16 * (nq * 4 + nt);
        s16x8 bf = *reinterpret_cast<const s16x8*>(&WB[n * 64 + ((kcl * 32 + kgrp) ^ xo)]);
        acc2[nt] = __builtin_amdgcn_mfma_f32_16x16x32_bf16(af, bf, acc2[nt], 0, 0, 0);
      }
    }
    __syncthreads();
  }
  // epilogue: write pred (f32 out, masked) + P1 bf16 (for mu)
#pragma unroll
  for (int nt = 0; nt < 4; ++nt) {
    int n = lm + 16 * (nq * 4 + nt);
    float bias = bo2[n];
#pragma unroll
    for (int rr = 0; rr < 4; ++rr) {
      int row = rbase + rr;
      float v = acc2[nt][rr] + bias; v = v > 0.f ? v : 0.f;
      if (row < 25) out[PRED_OFF + (b * NV + jbase + row) * 256 + n] = v;
      P1[row * 264 + n] = f2bf(v);
    }
  }
  // stage Wtmusw (512 uint4 = one per thread)
  reinterpret_cast<uint4*>(WB)[tid] = reinterpret_cast<const uint4*>(Wtmusw)[tid];
  __syncthreads();

  // mu: pred @ Wtmu (nq == 0 waves: both row tiles)
  if (nq == 0) {
    f32x4 accm = {0.f, 0.f, 0.f, 0.f};
#pragma unroll
    for (int kc = 0; kc < 8; ++kc) {
      s16x8 af = *reinterpret_cast<const s16x8*>(&P1[rowA * 264 + kc * 32 + kgrp]);
      s16x8 bf = *reinterpret_cast<const s16x8*>(&WB[lm * 256 + ((kc * 32 + kgrp) ^ xo)]);
      accm = __builtin_amdgcn_mfma_f32_16x16x32_bf16(af, bf, accm, 0, 0, 0);
    }
    float bias = bmu[lm];
#pragma unroll
    for (int rr = 0; rr < 4; ++rr) {
      int row = rbase + rr;
      if (row < 25) out[(b * NV + jbase + row) * 16 + lm] = accm[rr] + bias;
    }
  }
}

extern "C" void kernel_launch(void* const* d_in, const int* in_sizes, int n_in,
                              void* d_out, int out_size, void* d_ws, size_t ws_size,
                              hipStream_t stream) {
  const float* inputs = (const float*)d_in[0];
  const float* edges  = (const float*)d_in[1];
  const float* w1     = (const float*)d_in[2];
  const float* b1     = (const float*)d_in[3];
  const float* w2     = (const float*)d_in[4];
  const float* b2     = (const float*)d_in[5];
  const float* wo1    = (const float*)d_in[6];
  const float* bo1    = (const float*)d_in[7];
  const float* wo2    = (const float*)d_in[8];
  const float* bo2    = (const float*)d_in[9];
  const float* wmu    = (const float*)d_in[10];
  const float* bmu    = (const float*)d_in[11];
  float* out = (float*)d_out;

  char* ws = (char*)d_ws;
  unsigned short* W2t    = (unsigned short*)(ws + 3276800);
  unsigned short* W1t    = (unsigned short*)(ws + 3282944);
  unsigned short* Wt1sw  = (unsigned short*)(ws + 3295232);
  unsigned short* Wt2sw  = (unsigned short*)(ws + 3328000);
  unsigned short* Wtmusw = (unsigned short*)(ws + 3459072);

  k_tr<<<372, 256, 0, stream>>>(w1, w2, wo1, wo2, wmu, W2t, W1t, Wt1sw, Wt2sw, Wtmusw);
  k_all<<<dim3(512, 2), 512, 0, stream>>>(inputs, edges, b1, b2, W1t, W2t,
                                          Wt1sw, bo1, Wt2sw, bo2, Wtmusw, bmu, out);
}

// Round 18
// 50.289 us; speedup vs baseline: 2.6846x; 1.1201x over previous
//
#include <hip/hip_runtime.h>
#include <hip/hip_bf16.h>
#include <hip/hip_fp16.h>

#define BATCHN 512
#define NV 50
#define NE 2450
#define INSZ 16
#define MH 32
#define NH 256

typedef short s16x8 __attribute__((ext_vector_type(8)));
typedef _Float16 f16x8 __attribute__((ext_vector_type(8)));
typedef float f32x4 __attribute__((ext_vector_type(4)));
typedef float f32x2 __attribute__((ext_vector_type(2)));

#define PRED_OFF (BATCHN * NV * INSZ)   // 409600

// ---- ws layout (bytes) ----
// W2t    f16  [3][32][32]         : 3276800  .. 3282944
// W1t    bf16 [2][3][32][32]      : 3282944  .. 3295232
// Wt1sw  bf16 16384               : 3295232  .. 3328000   ([256][64] XOR-swizzled)
// Wt2sw  bf16 65536               : 3328000  .. 3459072   (4 x [256][64] swizzled)
// Wtmusw bf16 4096                : 3459072  .. 3467264   ([16][256] swizzled)

__device__ __forceinline__ unsigned short f2bf(float x) {
  unsigned int u = __float_as_uint(x);
  unsigned int r = (u + 0x7fffu + ((u >> 16) & 1u)) >> 16;  // RTNE
  return (unsigned short)r;
}
__device__ __forceinline__ unsigned short f2h(float x) {
  return __half_as_ushort(__float2half(x));  // RTNE f32->f16
}
__device__ __forceinline__ unsigned int pk2(float a, float b) {
  return (unsigned int)f2bf(a) | ((unsigned int)f2bf(b) << 16);
}
__device__ __forceinline__ unsigned int cvtpk(float lo, float hi) {
  unsigned int r;
  asm("v_cvt_pk_bf16_f32 %0, %1, %2" : "=v"(r) : "v"(lo), "v"(hi));
  return r;
}
__device__ __forceinline__ unsigned int pkmax0(unsigned int x, unsigned int z) {
  unsigned int r;
  asm("v_pk_max_i16 %0, %1, %2" : "=v"(r) : "v"(x), "v"(z));
  return r;
}
__device__ __forceinline__ unsigned int pkaddh(unsigned int a, unsigned int b) {
  unsigned int r;
  asm("v_pk_add_f16 %0, %1, %2" : "=v"(r) : "v"(a), "v"(b));
  return r;
}
__device__ __forceinline__ void pkfma(f32x2& acc, f32x2 a, f32x2 b) {
  asm("v_pk_fma_f32 %0, %1, %2, %0" : "+v"(acc) : "v"(a), "v"(b));
}

// ---------------- Kernel 1: weight transforms (unchanged) -------------------
__global__ void k_tr(const float* __restrict__ w1, const float* __restrict__ w2,
                     const float* __restrict__ wo1, const float* __restrict__ wo2,
                     const float* __restrict__ wmu,
                     unsigned short* __restrict__ W2t, unsigned short* __restrict__ W1t,
                     unsigned short* __restrict__ Wt1sw, unsigned short* __restrict__ Wt2sw,
                     unsigned short* __restrict__ Wtmusw) {
  int idx = blockIdx.x * 256 + threadIdx.x;
  if (idx < 3072) {                      // W2t[kk][h][c] = w2[(kk+1)*32 + c][h] (f16)
    int c = idx & 31, h = (idx >> 5) & 31, kk = idx >> 10;
    W2t[idx] = f2h(w2[((kk + 1) * 32 + c) * 32 + h]);
  } else if (idx < 9216) {               // W1t[half][kk][n][k] (bf16)
    int j = idx - 3072;
    int k = j & 31, n = (j >> 5) & 31, kk = (j >> 10) % 3, half = j / 3072;
    W1t[j] = f2bf(k < 16 ? w1[((kk + 1) * 32 + half * 16 + k) * 32 + n] : 0.f);
  } else if (idx < 9216 + 16384) {       // Wt1sw
    int j = idx - 9216; int n = j & 255, kl = j >> 8;
    float v = kl < 48 ? wo1[kl * 256 + n] : 0.f;
    Wt1sw[n * 64 + (kl ^ ((n & 7) << 3))] = f2bf(v);
  } else if (idx < 9216 + 16384 + 65536) { // Wt2sw
    int j = idx - (9216 + 16384);
    int c = j >> 14, r = j & 16383;
    int n = r & 255, kl = r >> 8;
    float v = wo2[(c * 64 + kl) * 256 + n];
    Wt2sw[(c * 256 + n) * 64 + (kl ^ ((n & 7) << 3))] = f2bf(v);
  } else if (idx < 9216 + 16384 + 65536 + 4096) { // Wtmusw
    int j = idx - (9216 + 16384 + 65536);
    int n = j & 15, kl = j >> 4;
    Wtmusw[n * 256 + (kl ^ ((n & 7) << 3))] = f2bf(wmu[kl * 16 + n]);
  }
}

// ---------------- Kernel 2: FUSED msg + out-MLP (one block per batch) --------
// 512 blocks x 512 thr (8 waves). Phase 1 = scheme-F f16 messages with a
// DUAL-STREAM sender loop (two independent acc sets -> 2x chains in flight)
// and T14 register-preload of Wt1sw (lands during phase 1). Phase 2 = R15
// out-MLP. LDS map identical to R15.
__global__ void __launch_bounds__(512, 4)
k_all(const float* __restrict__ inputs, const float* __restrict__ edges,
      const float* __restrict__ b1, const float* __restrict__ b2,
      const unsigned short* __restrict__ W1t, const unsigned short* __restrict__ W2t,
      const unsigned short* __restrict__ Wt1sw, const float* __restrict__ bo1,
      const unsigned short* __restrict__ Wt2sw, const float* __restrict__ bo2,
      const unsigned short* __restrict__ Wtmusw, const float* __restrict__ bmu,
      float* __restrict__ out) {
  __shared__ __align__(16) char smem[75776];
  unsigned short* S16 = (unsigned short*)(smem);           // [0, 10400)
  unsigned short* R16 = (unsigned short*)(smem + 10400);   // [10400, 20800)
  float* E_lds = (float*)(smem + 20800);                   // [20800, 54400)
  float* comb  = (float*)(smem + 10400);                   // overlays dead R16
  float* agg_l = (float*)(smem + 20800);                   // overlays dead E head
  unsigned short* aug = (unsigned short*)(smem);           // phase 2
  unsigned short* P1  = (unsigned short*)(smem + 9216);
  unsigned short* WB  = (unsigned short*)(smem + 43008);

  const int b   = blockIdx.x;
  const int tid = threadIdx.x;
  const int w   = tid >> 6;       // 0..7
  const int l   = tid & 63;
  const int grp = l >> 4;         // 0..3
  const int lm  = l & 15;
  const int jt  = w & 3;          // receiver tile / row tile
  const int ih  = w >> 2;         // sender parity / N-half

  // ======================= PHASE 1: messages =======================
  // stage E: E_lds[i][kk][js]; js >= 50 and diagonal = 0
  for (int x = tid; x < NV * 56; x += 512) {
    int i  = x / 56;
    int js = x - i * 56;
    float4 ev = make_float4(0.f, 0.f, 0.f, 0.f);
    if (js < NV && js != i) {
      int e = i * 49 + js - (js > i ? 1 : 0);
      ev = reinterpret_cast<const float4*>(edges)[b * NE + e];
    }
    int base = i * 168 + js;
    E_lds[base]       = ev.y;
    E_lds[base + 56]  = ev.z;
    E_lds[base + 112] = ev.w;
  }

  // in-block fc1 GEMM: R/S = inputs @ W1 halves (K=16 zero-padded), f16 out
  {
    const int half = w >> 2;
    const int mt4  = w & 3;
    int node  = mt4 * 16 + lm;
    int nodec = node < NV ? node : NV - 1;
    s16x8 af = {0, 0, 0, 0, 0, 0, 0, 0};
    if (grp < 2) {
      const float4* ip = reinterpret_cast<const float4*>(inputs) + (b * NV + nodec) * 4 + grp * 2;
      float4 x0 = ip[0], x1 = ip[1];
      union { unsigned int u[4]; s16x8 v; } U;
      U.u[0] = cvtpk(x0.x, x0.y); U.u[1] = cvtpk(x0.z, x0.w);
      U.u[2] = cvtpk(x1.x, x1.y); U.u[3] = cvtpk(x1.z, x1.w);
      af = U.v;
    }
    unsigned short* dst = half ? S16 : R16;
#pragma unroll
    for (int kk = 0; kk < 3; ++kk) {
#pragma unroll
      for (int nt = 0; nt < 2; ++nt) {
        int h = lm + 16 * nt;
        s16x8 bf = *reinterpret_cast<const s16x8*>(W1t + ((half * 3 + kk) * 32 + h) * 32 + grp * 8);
        f32x4 C;
        if (half == 0) { float bv = b1[(kk + 1) * 32 + h]; C = f32x4{bv, bv, bv, bv}; }
        else C = f32x4{0.f, 0.f, 0.f, 0.f};
        f32x4 o = __builtin_amdgcn_mfma_f32_16x16x32_bf16(af, bf, C, 0, 0, 0);
#pragma unroll
        for (int rr = 0; rr < 4; ++rr) {
          int n2 = mt4 * 16 + grp * 4 + rr;
          if (n2 < NV) dst[n2 * 104 + kk * 32 + h] = f2h(o[rr]);
        }
      }
    }
  }

  // per-wave persistent fragments (f16 W2 B-frags + f32 bias C)
  f16x8 Bf[3][2];
  f32x4 Cb[3][2];
#pragma unroll
  for (int kk = 0; kk < 3; ++kk)
#pragma unroll
    for (int nt = 0; nt < 2; ++nt) {
      int h = lm + 16 * nt;
      Bf[kk][nt] = *reinterpret_cast<const f16x8*>(W2t + (kk * 32 + h) * 32 + grp * 8);
      float bv = b2[(kk + 1) * 32 + h];
      Cb[kk][nt] = f32x4{bv, bv, bv, bv};
    }

  // T14: preload Wt1sw into registers; lands during phase 1, ds_write in phase 2
  uint4 wpre0 = reinterpret_cast<const uint4*>(Wt1sw)[tid];
  uint4 wpre1 = reinterpret_cast<const uint4*>(Wt1sw)[tid + 512];
  uint4 wpre2 = reinterpret_cast<const uint4*>(Wt1sw)[tid + 1024];
  uint4 wpre3 = reinterpret_cast<const uint4*>(Wt1sw)[tid + 1536];
  __syncthreads();

  // Rh: this wave's 16 receiver rows in f16 (12 u32)
  unsigned int Rh[3][4];
  {
    int jrow = jt * 16 + lm;
    int jr   = jrow < NV ? jrow : NV - 1;
#pragma unroll
    for (int kk = 0; kk < 3; ++kk) {
      uint4 rv = *reinterpret_cast<const uint4*>(&R16[jr * 104 + kk * 32 + grp * 8]);
      Rh[kk][0] = rv.x; Rh[kk][1] = rv.y; Rh[kk][2] = rv.z; Rh[kk][3] = rv.w;
    }
  }
  __syncthreads();   // R16 dead (comb overlays it)

  const int slot0 = jt * 16 + grp * 4;
  const int slot  = slot0 > 52 ? 52 : slot0;   // dead lanes -> zero region (50..55)

  // dual-stream accumulators
  f32x2 a0aA = {0.f, 0.f}, a0bA = {0.f, 0.f}, a1aA = {0.f, 0.f}, a1bA = {0.f, 0.f};
  f32x2 a0aB = {0.f, 0.f}, a0bB = {0.f, 0.f}, a1aB = {0.f, 0.f}, a1bB = {0.f, 0.f};

  auto UNIT = [&](int i, f32x2& c0a, f32x2& c0b, f32x2& c1a, f32x2& c1b) {
    const float* Eb = &E_lds[i * 168 + slot];
#pragma unroll
    for (int kk = 0; kk < 3; ++kk) {
      uint4 sv = *reinterpret_cast<const uint4*>(&S16[i * 104 + kk * 32 + grp * 8]);
      f32x4 ev = *reinterpret_cast<const f32x4*>(Eb + kk * 56);
      union { unsigned int u[4]; f16x8 v; } U;
      U.u[0] = pkmax0(pkaddh(Rh[kk][0], sv.x), 0u);
      U.u[1] = pkmax0(pkaddh(Rh[kk][1], sv.y), 0u);
      U.u[2] = pkmax0(pkaddh(Rh[kk][2], sv.z), 0u);
      U.u[3] = pkmax0(pkaddh(Rh[kk][3], sv.w), 0u);
      f32x4 d0 = __builtin_amdgcn_mfma_f32_16x16x32_f16(U.v, Bf[kk][0], Cb[kk][0], 0, 0, 0);
      f32x4 d1 = __builtin_amdgcn_mfma_f32_16x16x32_f16(U.v, Bf[kk][1], Cb[kk][1], 0, 0, 0);
      f32x2 ea = {ev[0], ev[1]}, eb = {ev[2], ev[3]};
      f32x2 r0a = {fmaxf(d0[0], 0.f), fmaxf(d0[1], 0.f)};
      f32x2 r0b = {fmaxf(d0[2], 0.f), fmaxf(d0[3], 0.f)};
      f32x2 r1a = {fmaxf(d1[0], 0.f), fmaxf(d1[1], 0.f)};
      f32x2 r1b = {fmaxf(d1[2], 0.f), fmaxf(d1[3], 0.f)};
      pkfma(c0a, r0a, ea); pkfma(c0b, r0b, eb);
      pkfma(c1a, r1a, ea); pkfma(c1b, r1b, eb);
    }
  };

  // streams: A = i in {ih, ih+2, ..., ih+22}; B = {ih+24, ..., ih+48}
#pragma unroll 2
  for (int t = 0; t < 12; ++t) {
    UNIT(ih + 2 * t,       a0aA, a0bA, a1aA, a1bA);
    UNIT(ih + 24 + 2 * t,  a0aB, a0bB, a1aB, a1bB);
  }
  UNIT(ih + 48, a0aB, a0bB, a1aB, a1bB);

  f32x2 acc0a = a0aA + a0aB, acc0b = a0bA + a0bB;
  f32x2 acc1a = a1aA + a1aB, acc1b = a1bA + a1bB;

  // combine parity waves; write agg into LDS
  if (ih == 1) {
    int cbase = (jt * 64 + l) * 10;
    *reinterpret_cast<f32x2*>(&comb[cbase])     = acc0a;
    *reinterpret_cast<f32x2*>(&comb[cbase + 2]) = acc0b;
    *reinterpret_cast<f32x2*>(&comb[cbase + 4]) = acc1a;
    *reinterpret_cast<f32x2*>(&comb[cbase + 6]) = acc1b;
  }
  __syncthreads();
  if (ih == 0) {
    int cbase = (jt * 64 + l) * 10;
    acc0a += *reinterpret_cast<const f32x2*>(&comb[cbase]);
    acc0b += *reinterpret_cast<const f32x2*>(&comb[cbase + 2]);
    acc1a += *reinterpret_cast<const f32x2*>(&comb[cbase + 4]);
    acc1b += *reinterpret_cast<const f32x2*>(&comb[cbase + 6]);
    float a0v[4] = {acc0a[0], acc0a[1], acc0b[0], acc0b[1]};
    float a1v[4] = {acc1a[0], acc1a[1], acc1b[0], acc1b[1]};
#pragma unroll
    for (int rr = 0; rr < 4; ++rr) {
      int j = jt * 16 + grp * 4 + rr;
      if (j < NV) {
        agg_l[j * 32 + lm]      = a0v[rr];
        agg_l[j * 32 + 16 + lm] = a1v[rr];
      }
    }
  }
  __syncthreads();

  // ======================= PHASE 2: out-MLP =======================
  const int xo = (lm & 7) << 3;

  // aug build (waves 0-3) + write preloaded Wt1sw into WB
  if (tid < 256) {
    int row = tid >> 2, q = tid & 3;
    uint2 u0; uint4 u1;
    if (row < NV) {
      float4 iv = reinterpret_cast<const float4*>(inputs)[(b * NV + row) * 4 + q];
      u0.x = pk2(iv.x, iv.y); u0.y = pk2(iv.z, iv.w);
      f32x4 a0 = *reinterpret_cast<const f32x4*>(&agg_l[row * 32 + q * 8]);
      f32x4 a1 = *reinterpret_cast<const f32x4*>(&agg_l[row * 32 + q * 8 + 4]);
      u1.x = pk2(a0[0], a0[1]); u1.y = pk2(a0[2], a0[3]);
      u1.z = pk2(a1[0], a1[1]); u1.w = pk2(a1[2], a1[3]);
    } else { u0.x = u0.y = 0u; u1.x = u1.y = u1.z = u1.w = 0u; }
    *reinterpret_cast<uint2*>(&aug[row * 72 + q * 4]) = u0;
    *reinterpret_cast<uint4*>(&aug[row * 72 + 16 + q * 8]) = u1;
    uint2 uz; uz.x = 0u; uz.y = 0u;
    *reinterpret_cast<uint2*>(&aug[row * 72 + 48 + q * 4]) = uz;
  }
  reinterpret_cast<uint4*>(WB)[tid]        = wpre0;
  reinterpret_cast<uint4*>(WB)[tid + 512]  = wpre1;
  reinterpret_cast<uint4*>(WB)[tid + 1024] = wpre2;
  reinterpret_cast<uint4*>(WB)[tid + 1536] = wpre3;
  __syncthreads();

  const int rowA  = 16 * jt + lm;
  const int kgrp  = grp * 8;
  const int rbase = 16 * jt + grp * 4;
  const int n0    = ih * 8;       // this wave's nt offset

  // fc1: aug[64x64] @ Wt1 -> P1
  f32x4 acc1[8];
#pragma unroll
  for (int nt = 0; nt < 8; ++nt) acc1[nt] = f32x4{0.f, 0.f, 0.f, 0.f};
#pragma unroll
  for (int kc = 0; kc < 2; ++kc) {
    s16x8 af = *reinterpret_cast<const s16x8*>(&aug[rowA * 72 + kc * 32 + kgrp]);
#pragma unroll
    for (int nt = 0; nt < 8; ++nt) {
      int n = lm + 16 * (n0 + nt);
      s16x8 bf = *reinterpret_cast<const s16x8*>(&WB[n * 64 + ((kc * 32 + kgrp) ^ xo)]);
      acc1[nt] = __builtin_amdgcn_mfma_f32_16x16x32_bf16(af, bf, acc1[nt], 0, 0, 0);
    }
  }
#pragma unroll
  for (int nt = 0; nt < 8; ++nt) {
    int n = lm + 16 * (n0 + nt);
    float bias = bo1[n];
#pragma unroll
    for (int rr = 0; rr < 4; ++rr) {
      float v = acc1[nt][rr] + bias; v = v > 0.f ? v : 0.f;
      P1[(rbase + rr) * 264 + n] = f2bf(v);
    }
  }
  __syncthreads();   // WB (Wt1) readers + P1 writers done

  // fc2: P1 @ Wt2 (4 staged chunks)
  f32x4 acc2[8];
#pragma unroll
  for (int nt = 0; nt < 8; ++nt) acc2[nt] = f32x4{0.f, 0.f, 0.f, 0.f};
  for (int c = 0; c < 4; ++c) {
    const uint4* src = reinterpret_cast<const uint4*>(Wt2sw + c * 16384);
    for (int i2 = tid; i2 < 2048; i2 += 512) reinterpret_cast<uint4*>(WB)[i2] = src[i2];
    __syncthreads();
#pragma unroll
    for (int kcl = 0; kcl < 2; ++kcl) {
      int kc = c * 2 + kcl;
      s16x8 af = *reinterpret_cast<const s16x8*>(&P1[rowA * 264 + kc * 32 + kgrp]);
#pragma unroll
      for (int nt = 0; nt < 8; ++nt) {
        int n = lm + 16 * (n0 + nt);
        s16x8 bf = *reinterpret_cast<const s16x8*>(&WB[n * 64 + ((kcl * 32 + kgrp) ^ xo)]);
        acc2[nt] = __builtin_amdgcn_mfma_f32_16x16x32_bf16(af, bf, acc2[nt], 0, 0, 0);
      }
    }
    __syncthreads();
  }
  // epilogue: write pred (f32 out, masked) + P1 bf16 (for mu)
#pragma unroll
  for (int nt = 0; nt < 8; ++nt) {
    int n = lm + 16 * (n0 + nt);
    float bias = bo2[n];
#pragma unroll
    for (int rr = 0; rr < 4; ++rr) {
      int row = rbase + rr;
      float v = acc2[nt][rr] + bias; v = v > 0.f ? v : 0.f;
      if (row < NV) out[PRED_OFF + (b * NV + row) * 256 + n] = v;
      P1[row * 264 + n] = f2bf(v);
    }
  }
  // stage Wtmusw (512 uint4 = one per thread)
  reinterpret_cast<uint4*>(WB)[tid] = reinterpret_cast<const uint4*>(Wtmusw)[tid];
  __syncthreads();

  // mu: pred @ Wtmu (N-half 0 waves only)
  if (ih == 0) {
    f32x4 accm = {0.f, 0.f, 0.f, 0.f};
#pragma unroll
    for (int kc = 0; kc < 8; ++kc) {
      s16x8 af = *reinterpret_cast<const s16x8*>(&P1[rowA * 264 + kc * 32 + kgrp]);
      s16x8 bf = *reinterpret_cast<const s16x8*>(&WB[lm * 256 + ((kc * 32 + kgrp) ^ xo)]);
      accm = __builtin_amdgcn_mfma_f32_16x16x32_bf16(af, bf, accm, 0, 0, 0);
    }
    float bias = bmu[lm];
#pragma unroll
    for (int rr = 0; rr < 4; ++rr) {
      int row = rbase + rr;
      if (row < NV) out[(b * NV + row) * 16 + lm] = accm[rr] + bias;
    }
  }
}

extern "C" void kernel_launch(void* const* d_in, const int* in_sizes, int n_in,
                              void* d_out, int out_size, void* d_ws, size_t ws_size,
                              hipStream_t stream) {
  const float* inputs = (const float*)d_in[0];
  const float* edges  = (const float*)d_in[1];
  const float* w1     = (const float*)d_in[2];
  const float* b1     = (const float*)d_in[3];
  const float* w2     = (const float*)d_in[4];
  const float* b2     = (const float*)d_in[5];
  const float* wo1    = (const float*)d_in[6];
  const float* bo1    = (const float*)d_in[7];
  const float* wo2    = (const float*)d_in[8];
  const float* bo2    = (const float*)d_in[9];
  const float* wmu    = (const float*)d_in[10];
  const float* bmu    = (const float*)d_in[11];
  float* out = (float*)d_out;

  char* ws = (char*)d_ws;
  unsigned short* W2t    = (unsigned short*)(ws + 3276800);
  unsigned short* W1t    = (unsigned short*)(ws + 3282944);
  unsigned short* Wt1sw  = (unsigned short*)(ws + 3295232);
  unsigned short* Wt2sw  = (unsigned short*)(ws + 3328000);
  unsigned short* Wtmusw = (unsigned short*)(ws + 3459072);

  k_tr<<<372, 256, 0, stream>>>(w1, w2, wo1, wo2, wmu, W2t, W1t, Wt1sw, Wt2sw, Wtmusw);
  k_all<<<512, 512, 0, stream>>>(inputs, edges, b1, b2, W1t, W2t,
                                 Wt1sw, bo1, Wt2sw, bo2, Wtmusw, bmu, out);
}